// Round 10
// baseline (423.326 us; speedup 1.0000x reference)
//
#include <hip/hip_runtime.h>
#include <hip/hip_bf16.h>

// Problem dims
#define BB    16
#define LL    4096
#define DIN   100
#define HD    256
#define NN    32
#define DHID  512
#define DOUT  100
#define MROWS (BB*LL)  // 65536
#define CH    64       // scan chunk length
#define CC    64       // chunks per sequence
#define NCH   (BB*CC)  // 1024 total chunks

// ws layout (float offsets). Total 27969152 floats (~111.9 MB).
#define OFF_WRE    0
#define OFF_WIM    8192
#define OFF_KRE    16384
#define OFF_KIM    24576
#define OFF_WCHR   32768
#define OFF_WCHI   40960
#define OFF_ENCB   49152
#define OFF_DSK    49408
#define OFF_LNG    49664
#define OFF_LNB    49920
#define OFF_B1     50176
#define OFF_B2     50688
#define OFF_WENCB  50816                // bf16 [256][128]
#define OFF_W1B    67200                // bf16 [512][256]
#define OFF_W2B    132736               // bf16 [128pad][512]
#define OFF_WFL    165504               // fp32 powers [h][d=0..64][comp=64]
#define OFF_BY     1230464              // bf16 [h][j=64][k=128] (Tker | KW)
#define OFF_VST    2279040              // bf16 [h][comp=64][i=64]
#define OFF_UH     2803328              // bf16 U [h][l]; G0 overlays after ln2
#define OFF_S      11191936             // bf16 S [chunk][h][comp]; Tb [l][h] overlays
#define OFF_YH     19580544             // bf16 y [h][l]; G1 overlays after ln2
#define OFF_TB     OFF_S
#define OFF_G0     OFF_UH
#define OFF_G1     OFF_YH

typedef __bf16 bf16x8 __attribute__((ext_vector_type(8)));
typedef float  f32x4  __attribute__((ext_vector_type(4)));

static __device__ __forceinline__ int probe_bf16(const void* lng) {
    return ((const unsigned int*)lng)[0] != 0x3f800000u;
}
static __device__ __forceinline__ float ldin(const void* p, long i, int isbf) {
    return isbf ? __bfloat162float(((const __hip_bfloat16*)p)[i]) : ((const float*)p)[i];
}
static __device__ __forceinline__ unsigned short f2bf(float v) {
    union { float f; unsigned u; } c; c.f = v;
    unsigned r = c.u + 0x7fffu + ((c.u >> 16) & 1u);
    return (unsigned short)(r >> 16);
}
static __device__ __forceinline__ float bf2f(unsigned short v) {
    union { unsigned u; float f; } c; c.u = ((unsigned)v) << 16; return c.f;
}
static __device__ __forceinline__ float gelu_exact(float x) {
    return 0.5f * x * (1.0f + erff(x * 0.70710678118654752f));
}

// ---------------- K0: derived SSM params + power table + weight convert ----------------
__global__ __launch_bounds__(256) void k_prep(
    const void* encw, const void* encb, const void* logdt, const void* loga,
    const void* aim, const void* bre, const void* bim, const void* cre,
    const void* cim, const void* dsk, const void* lng, const void* lnb,
    const void* w1, const void* b1, const void* w2, const void* b2, float* ws)
{
    const int isbf = probe_bf16(lng);
    unsigned short* WEB = (unsigned short*)(ws + OFF_WENCB);
    unsigned short* W1B = (unsigned short*)(ws + OFF_W1B);
    unsigned short* W2B = (unsigned short*)(ws + OFF_W2B);
    const int total = 8192 + 256*4 + 512 + 128 + 32768 + 131072 + 65536;
    for (int idx = blockIdx.x * blockDim.x + threadIdx.x; idx < total;
         idx += gridDim.x * blockDim.x) {
        int i = idx;
        if (i < 8192) {
            int h = i >> 5;
            float dt  = expf(ldin(logdt, h, isbf));
            float Are = -expf(ldin(loga, i, isbf));
            float Aim = ldin(aim, i, isbf);
            float er  = expf(dt * Are);
            float sv, cv; sincosf(dt * Aim, &sv, &cv);
            float wre = er * cv, wim = er * sv;
            float Bre = ldin(bre, i, isbf), Bim = ldin(bim, i, isbf);
            float Cre = ldin(cre, i, isbf), Cim = ldin(cim, i, isbf);
            float C0re = Bre*Cre - Bim*Cim;
            float C0im = Bre*Cim + Bim*Cre;
            float inv = 1.0f / (Are*Are + Aim*Aim);
            float nre = wre - 1.0f, nim = wim;
            float Zre = (nre*Are + nim*Aim) * inv;
            float Zim = (nim*Are - nre*Aim) * inv;
            float kre = 2.0f * (C0re*Zre - C0im*Zim);
            float kim = -2.0f * (C0re*Zim + C0im*Zre);
            ws[OFF_WRE + i] = wre;  ws[OFF_WIM + i] = wim;
            ws[OFF_KRE + i] = kre;  ws[OFF_KIM + i] = kim;
            float* Wf = ws + OFF_WFL + (long)h * 4160 + 2*(i & 31);
            float pr = 1.0f, pi = 0.0f;
            for (int d = 0; d <= 64; ++d) {
                Wf[d*64]     = pr;
                Wf[d*64 + 1] = pi;
                float tr = pr*wre - pi*wim;
                pi = pr*wim + pi*wre; pr = tr;
            }
            ws[OFF_WCHR + i] = Wf[64*64];
            ws[OFF_WCHI + i] = Wf[64*64 + 1];
        } else if ((i -= 8192) < 256) {
            ws[OFF_ENCB + i] = ldin(encb, i, isbf);
        } else if ((i -= 256) < 256) {
            ws[OFF_DSK + i] = ldin(dsk, i, isbf);
        } else if ((i -= 256) < 256) {
            ws[OFF_LNG + i] = ldin(lng, i, isbf);
        } else if ((i -= 256) < 256) {
            ws[OFF_LNB + i] = ldin(lnb, i, isbf);
        } else if ((i -= 256) < 512) {
            ws[OFF_B1 + i] = ldin(b1, i, isbf);
        } else if ((i -= 512) < 128) {
            ws[OFF_B2 + i] = (i < 100) ? ldin(b2, i, isbf) : 0.0f;
        } else if ((i -= 128) < 32768) {
            int h = i >> 7, k = i & 127;
            WEB[i] = (k < 100) ? f2bf(ldin(encw, (long)h*100 + k, isbf)) : (unsigned short)0;
        } else if ((i -= 32768) < 131072) {
            W1B[i] = f2bf(ldin(w1, i, isbf));
        } else if ((i -= 131072) < 65536) {
            int j = i >> 9, k = i & 511;
            W2B[i] = (j < 100) ? f2bf(ldin(w2, (long)j*512 + k, isbf)) : (unsigned short)0;
        }
    }
}

// ---------------- K0b: build conv taps Tker, correction KW (-> BY) and Vst ----------------
__global__ __launch_bounds__(256) void k_tker(float* ws)
{
    __shared__ float Wp[65*65];
    __shared__ float kr[32], ki[32], Ks[64];
    int h = blockIdx.x;
    int t = threadIdx.x;
    for (int idx = t; idx < 4160; idx += 256) {
        int d = idx >> 6, c = idx & 63;
        Wp[d*65 + c] = ws[OFF_WFL + (long)h*4160 + idx];
    }
    if (t < 32) kr[t] = ws[OFF_KRE + h*32 + t];
    else if (t < 64) ki[t-32] = ws[OFF_KIM + h*32 + (t-32)];
    __syncthreads();
    if (t < 64) {
        float s = 0.0f;
        #pragma unroll
        for (int n = 0; n < 32; ++n)
            s += kr[n]*Wp[t*65 + 2*n] + ki[n]*Wp[t*65 + 2*n + 1];
        Ks[t] = s;
    }
    __syncthreads();
    unsigned short* BY = (unsigned short*)(ws + OFF_BY) + (long)h*8192;
    for (int idx = t; idx < 8192; idx += 256) {
        int j = idx >> 7, k = idx & 127;
        float v;
        if (k < 64) {
            v = (k <= j) ? Ks[j - k] : 0.0f;
        } else {
            int c = k - 64, n = c >> 1;
            float pr = Wp[(j+1)*65 + 2*n], pi = Wp[(j+1)*65 + 2*n + 1];
            v = ((c & 1) == 0) ? (kr[n]*pr + ki[n]*pi) : (ki[n]*pr - kr[n]*pi);
        }
        BY[idx] = f2bf(v);
    }
    unsigned short* Vst = (unsigned short*)(ws + OFF_VST) + (long)h*4096;
    for (int idx = t; idx < 4096; idx += 256) {
        int comp = idx >> 6, i = idx & 63;
        Vst[idx] = f2bf(Wp[(63 - i)*65 + comp]);
    }
}

// ---------------- K1: encoder MFMA GEMM -> Uh bf16 [h][l], LDS-staged epilogue ----------
__global__ __launch_bounds__(256) void k_encm(const void* x, const void* lng, float* ws)
{
    const int isbf = probe_bf16(lng);
    __shared__ unsigned short SM[18432];
    unsigned short (*As)[72] = (unsigned short(*)[72])SM;
    unsigned short (*Bs)[72] = (unsigned short(*)[72])(SM + 9216);
    unsigned short* Cs = SM;
    const unsigned short* WEB = (const unsigned short*)(ws + OFF_WENCB);
    int bid = blockIdx.x;
    int rt = bid >> 1, ct = bid & 1;
    long row0 = (long)rt * 128;
    int c0 = ct * 128;
    int t = threadIdx.x;
    int lane = t & 63, wv = t >> 6;
    int wm = (wv & 1) * 64, wn = (wv >> 1) * 64;
    int quad = lane >> 4, mr = lane & 15;
    f32x4 acc[4][4] = {};
    for (int kc = 0; kc < 2; ++kc) {
        int k0 = kc * 64;
        for (int idx = t; idx < 128*64; idx += 256) {
            int r = idx >> 6, k = idx & 63;
            int kg = k0 + k;
            float v = (kg < 100) ? ldin(x, (row0 + r)*100 + kg, isbf) : 0.0f;
            As[r][k] = f2bf(v);
        }
        for (int idx = t; idx < 128*32; idx += 256) {
            int r = idx >> 5, kk = idx & 31;
            ((unsigned int*)&Bs[r][0])[kk] =
                ((const unsigned int*)WEB)[((c0 + r) * 128 + k0) / 2 + kk];
        }
        __syncthreads();
        #pragma unroll
        for (int ks = 0; ks < 64; ks += 32) {
            bf16x8 af[4], bfr[4];
            #pragma unroll
            for (int i = 0; i < 4; ++i)
                af[i] = *(const bf16x8*)&As[wm + i*16 + mr][ks + quad*8];
            #pragma unroll
            for (int j = 0; j < 4; ++j)
                bfr[j] = *(const bf16x8*)&Bs[wn + j*16 + mr][ks + quad*8];
            #pragma unroll
            for (int i = 0; i < 4; ++i)
                #pragma unroll
                for (int j = 0; j < 4; ++j)
                    acc[i][j] = __builtin_amdgcn_mfma_f32_16x16x32_bf16(af[i], bfr[j], acc[i][j], 0, 0, 0);
        }
        __syncthreads();
    }
    const float* eb = ws + OFF_ENCB;
    #pragma unroll
    for (int j = 0; j < 4; ++j) {
        int hloc = wn + j*16 + mr;
        float bb = eb[c0 + hloc];
        #pragma unroll
        for (int i = 0; i < 4; ++i) {
            int l0 = wm + i*16 + quad*4;
            unsigned short pk[4];
            #pragma unroll
            for (int reg = 0; reg < 4; ++reg)
                pk[reg] = f2bf(acc[i][j][reg] + bb);
            *(uint2*)&Cs[hloc*136 + l0] = *(uint2*)pk;
        }
    }
    __syncthreads();
    unsigned short* Uh = (unsigned short*)(ws + OFF_UH);
    #pragma unroll
    for (int it = 0; it < 8; ++it) {
        int idx = t + it*256;
        int hh = idx >> 4, f = idx & 15;
        *(float4*)&Uh[(long)(c0 + hh)*65536 + row0 + f*8] = *(const float4*)&Cs[hh*136 + f*8];
    }
}

// ---------------- K2: chunk-final zero-init states via MFMA: S = U_chunk x Vst^T --------
__global__ __launch_bounds__(256) void k_state(float* ws)
{
    __shared__ unsigned short As[128][72];
    __shared__ unsigned short Bs[64][72];
    const unsigned short* Uh  = (const unsigned short*)(ws + OFF_UH);
    const unsigned short* Vst = (const unsigned short*)(ws + OFF_VST);
    int bid = blockIdx.x;
    int h = bid >> 3, ct = bid & 7;
    int c0r = ct * 128;
    int t = threadIdx.x;
    int lane = t & 63, wv = t >> 6;
    int wm = (wv & 1) * 64, wn = (wv >> 1) * 32;
    int quad = lane >> 4, mr = lane & 15;
    const unsigned short* Ubase = Uh + (long)h * 65536;
    #pragma unroll
    for (int it = 0; it < 4; ++it) {
        int idx = t + it*256;
        int r = idx >> 3, f = idx & 7;
        *(float4*)&As[r][f*8] = *(const float4*)&Ubase[(long)(c0r + r)*64 + f*8];
    }
    #pragma unroll
    for (int it = 0; it < 2; ++it) {
        int idx = t + it*256;
        int r = idx >> 3, f = idx & 7;
        *(float4*)&Bs[r][f*8] = *(const float4*)&Vst[(long)h*4096 + r*64 + f*8];
    }
    __syncthreads();
    f32x4 acc[4][2] = {};
    #pragma unroll
    for (int ks = 0; ks < 64; ks += 32) {
        bf16x8 af[4], bfr[2];
        #pragma unroll
        for (int i = 0; i < 4; ++i)
            af[i] = *(const bf16x8*)&As[wm + i*16 + mr][ks + quad*8];
        #pragma unroll
        for (int jn = 0; jn < 2; ++jn)
            bfr[jn] = *(const bf16x8*)&Bs[wn + jn*16 + mr][ks + quad*8];
        #pragma unroll
        for (int i = 0; i < 4; ++i)
            #pragma unroll
            for (int jn = 0; jn < 2; ++jn)
                acc[i][jn] = __builtin_amdgcn_mfma_f32_16x16x32_bf16(af[i], bfr[jn], acc[i][jn], 0, 0, 0);
    }
    __syncthreads();
    unsigned short* Cs = &As[0][0];
    #pragma unroll
    for (int jn = 0; jn < 2; ++jn) {
        int c = wn + jn*16 + mr;
        #pragma unroll
        for (int i = 0; i < 4; ++i)
            #pragma unroll
            for (int reg = 0; reg < 4; ++reg)
                Cs[(wm + i*16 + quad*4 + reg)*72 + c] = f2bf(acc[i][jn][reg]);
    }
    __syncthreads();
    unsigned short* S = (unsigned short*)(ws + OFF_S);
    #pragma unroll
    for (int it = 0; it < 4; ++it) {
        int idx = t + it*256;
        int r = idx >> 3, f = idx & 7;
        *(float4*)&S[(long)(c0r + r)*16384 + h*64 + f*8] = *(const float4*)&Cs[r*72 + f*8];
    }
}

// ---------------- K3: chunk-level propagation, in place S (final) -> s0 (init) ----------
__global__ __launch_bounds__(256) void k_chunk(float* ws)
{
    int tid = blockIdx.x * 256 + threadIdx.x;
    int b = tid >> 13;
    int h = (tid >> 5) & 255;
    int n = tid & 31;
    int i = h * NN + n;
    float wr = ws[OFF_WCHR + i], wi = ws[OFF_WCHI + i];
    unsigned int* Su = (unsigned int*)(ws + OFF_S);
    long a0 = (long)(b * CC) * 8192 + h * 32 + n;
    float rr = 0.0f, ri = 0.0f;
    unsigned int vnext = Su[a0];
    for (int c = 0; c < CC; ++c) {
        long a = a0 + (long)c * 8192;
        unsigned int v = vnext;
        if (c + 1 < CC) vnext = Su[a + 8192];
        float Sr = bf2f((unsigned short)(v & 0xFFFFu));
        float Si = bf2f((unsigned short)(v >> 16));
        Su[a] = (unsigned int)f2bf(rr) | ((unsigned int)f2bf(ri) << 16);
        float nr = fmaf(wr, rr, fmaf(-wi, ri, Sr));
        float ni = fmaf(wr, ri, fmaf(wi, rr, Si));
        rr = nr; ri = ni;
    }
}

// ---------------- K4: fused y = conv(u) + KW*s0 via MFMA, K=128 -> Yh [h][l] --------
__global__ __launch_bounds__(256) void k_y(float* ws)
{
    __shared__ unsigned short As[128][136];
    __shared__ unsigned short Bs[64][136];
    const unsigned short* Uh = (const unsigned short*)(ws + OFF_UH);
    const unsigned short* S  = (const unsigned short*)(ws + OFF_S);
    const unsigned short* BY = (const unsigned short*)(ws + OFF_BY);
    int bid = blockIdx.x;
    int h = bid >> 3, ct = bid & 7;
    int c0r = ct * 128;
    int t = threadIdx.x;
    int lane = t & 63, wv = t >> 6;
    int wm = (wv & 1) * 64, wn = (wv >> 1) * 32;
    int quad = lane >> 4, mr = lane & 15;
    #pragma unroll
    for (int it = 0; it < 8; ++it) {
        int idx = t + it*256;
        int r = idx >> 4, f = idx & 15;
        const unsigned short* src = (f < 8)
            ? &Uh[(long)h*65536 + (long)(c0r + r)*64 + f*8]
            : &S[(long)(c0r + r)*16384 + h*64 + (f-8)*8];
        *(float4*)&As[r][f*8] = *(const float4*)src;
    }
    #pragma unroll
    for (int it = 0; it < 4; ++it) {
        int idx = t + it*256;
        int r = idx >> 4, f = idx & 15;
        *(float4*)&Bs[r][f*8] = *(const float4*)&BY[(long)h*8192 + r*128 + f*8];
    }
    __syncthreads();
    f32x4 acc[4][2] = {};
    #pragma unroll
    for (int ks = 0; ks < 128; ks += 32) {
        bf16x8 af[4], bfr[2];
        #pragma unroll
        for (int i = 0; i < 4; ++i)
            af[i] = *(const bf16x8*)&As[wm + i*16 + mr][ks + quad*8];
        #pragma unroll
        for (int jn = 0; jn < 2; ++jn)
            bfr[jn] = *(const bf16x8*)&Bs[wn + jn*16 + mr][ks + quad*8];
        #pragma unroll
        for (int i = 0; i < 4; ++i)
            #pragma unroll
            for (int jn = 0; jn < 2; ++jn)
                acc[i][jn] = __builtin_amdgcn_mfma_f32_16x16x32_bf16(af[i], bfr[jn], acc[i][jn], 0, 0, 0);
    }
    __syncthreads();
    unsigned short* Cs = &As[0][0];
    #pragma unroll
    for (int jn = 0; jn < 2; ++jn) {
        int c = wn + jn*16 + mr;
        #pragma unroll
        for (int i = 0; i < 4; ++i)
            #pragma unroll
            for (int reg = 0; reg < 4; ++reg)
                Cs[(wm + i*16 + quad*4 + reg)*136 + c] = f2bf(acc[i][jn][reg]);
    }
    __syncthreads();
    unsigned short* Yh = (unsigned short*)(ws + OFF_YH);
    #pragma unroll
    for (int it = 0; it < 4; ++it) {
        int idx = t + it*256;
        int r = idx >> 3, f = idx & 7;
        *(float4*)&Yh[(long)h*65536 + (long)(c0r + r)*64 + f*8] = *(const float4*)&Cs[r*136 + f*8];
    }
}

// ---------------- K5: fused Dskip+GELU+residual+LayerNorm -> Tb [l][h] (over S) ----------
__global__ __launch_bounds__(1024) void k_ln2(float* ws)
{
    __shared__ unsigned short Vs[64][258];
    __shared__ float parts[64][17], partq[64][17];
    __shared__ float Ms[64], Rs[64];
    __shared__ float Dls[256], Gls[256], Bls[256];
    int chunk = blockIdx.x;
    int t = threadIdx.x;
    if (t < 256) { Dls[t] = ws[OFF_DSK + t]; Gls[t] = ws[OFF_LNG + t]; Bls[t] = ws[OFF_LNB + t]; }
    __syncthreads();
    const unsigned short* Uh = (const unsigned short*)(ws + OFF_UH);
    const unsigned short* Yh = (const unsigned short*)(ws + OFF_YH);
    int j = t & 63, hg = t >> 6;
    float ps = 0.0f, pq = 0.0f;
    #pragma unroll 4
    for (int k = 0; k < 16; ++k) {
        int h = hg*16 + k;
        long base = (long)h*65536 + chunk*64;
        float u = bf2f(Uh[base + j]);
        float y = bf2f(Yh[base + j]);
        float v = gelu_exact(fmaf(Dls[h], u, y)) + u;
        Vs[j][h] = f2bf(v);
        ps += v; pq += v*v;
    }
    parts[j][hg] = ps; partq[j][hg] = pq;
    __syncthreads();
    if (t < 64) {
        float s = 0.0f, q = 0.0f;
        #pragma unroll
        for (int g = 0; g < 16; ++g) { s += parts[t][g]; q += partq[t][g]; }
        float mean = s * (1.0f/256.0f);
        float var  = q * (1.0f/256.0f) - mean*mean;
        Ms[t] = mean; Rs[t] = rsqrtf(var + 1e-5f);
    }
    __syncthreads();
    unsigned short* Tb = (unsigned short*)(ws + OFF_TB);
    int h2 = t & 255, jg = t >> 8;
    #pragma unroll 4
    for (int jj = 0; jj < 16; ++jj) {
        int j2 = jg*16 + jj;
        float v = bf2f(Vs[j2][h2]);
        Tb[((long)chunk*64 + j2)*256 + h2] = f2bf((v - Ms[j2]) * Rs[j2] * Gls[h2] + Bls[h2]);
    }
}

// ---------------- K6: dec1 MFMA GEMM + GELU -> G, 256x128 tile, VGPR prefetch ----------
__global__ __launch_bounds__(256, 2) void k_dec1m(float* ws)
{
    __shared__ unsigned short SM[27648];   // As 256x72 (18432), Bs 128x72 (9216)
    unsigned short (*As)[72] = (unsigned short(*)[72])SM;
    unsigned short (*Bs)[72] = (unsigned short(*)[72])(SM + 18432);
    unsigned short* Cs = SM;               // epilogue: 128x136 per half
    const unsigned short* Tb  = (const unsigned short*)(ws + OFF_TB);
    const unsigned short* W1B = (const unsigned short*)(ws + OFF_W1B);
    int bid = blockIdx.x;                  // 256 row tiles x 4 col tiles
    int rt = bid >> 2, ct = bid & 3;
    long row0 = (long)rt * 256;
    int c0 = ct * 128;
    int t = threadIdx.x;
    int lane = t & 63, wv = t >> 6;
    int wm = (wv & 1) * 128, wn = (wv >> 1) * 64;
    int quad = lane >> 4, mr = lane & 15;
    f32x4 acc[8][4] = {};
    float4 pa[8], pb[4];
    #pragma unroll
    for (int it = 0; it < 8; ++it) {
        int idx = t + it*256; int r = idx >> 3, f = idx & 7;
        pa[it] = *(const float4*)&Tb[(row0 + r)*256 + f*8];
    }
    #pragma unroll
    for (int it = 0; it < 4; ++it) {
        int idx = t + it*256; int r = idx >> 3, f = idx & 7;
        pb[it] = *(const float4*)&W1B[(long)(c0 + r)*256 + f*8];
    }
    for (int kc = 0; kc < 4; ++kc) {
        #pragma unroll
        for (int it = 0; it < 8; ++it) {
            int idx = t + it*256; int r = idx >> 3, f = idx & 7;
            *(float4*)&As[r][f*8] = pa[it];
        }
        #pragma unroll
        for (int it = 0; it < 4; ++it) {
            int idx = t + it*256; int r = idx >> 3, f = idx & 7;
            *(float4*)&Bs[r][f*8] = pb[it];
        }
        __syncthreads();
        if (kc < 3) {
            int k0 = (kc + 1) * 64;
            #pragma unroll
            for (int it = 0; it < 8; ++it) {
                int idx = t + it*256; int r = idx >> 3, f = idx & 7;
                pa[it] = *(const float4*)&Tb[(row0 + r)*256 + k0 + f*8];
            }
            #pragma unroll
            for (int it = 0; it < 4; ++it) {
                int idx = t + it*256; int r = idx >> 3, f = idx & 7;
                pb[it] = *(const float4*)&W1B[(long)(c0 + r)*256 + k0 + f*8];
            }
        }
        #pragma unroll
        for (int ks = 0; ks < 64; ks += 32) {
            bf16x8 af[8], bfr[4];
            #pragma unroll
            for (int i = 0; i < 8; ++i)
                af[i] = *(const bf16x8*)&As[wm + i*16 + mr][ks + quad*8];
            #pragma unroll
            for (int j = 0; j < 4; ++j)
                bfr[j] = *(const bf16x8*)&Bs[wn + j*16 + mr][ks + quad*8];
            #pragma unroll
            for (int i = 0; i < 8; ++i)
                #pragma unroll
                for (int j = 0; j < 4; ++j)
                    acc[i][j] = __builtin_amdgcn_mfma_f32_16x16x32_bf16(af[i], bfr[j], acc[i][j], 0, 0, 0);
        }
        __syncthreads();
    }
    const float* b1 = ws + OFF_B1;
    unsigned short* G = (unsigned short*)(ws + ((ct < 2) ? OFF_G0 : OFF_G1));
    int cl0 = (ct < 2) ? c0 : (c0 - 256);
    #pragma unroll
    for (int half = 0; half < 2; ++half) {
        if ((wv & 1) == half) {
            #pragma unroll
            for (int j = 0; j < 4; ++j) {
                int cloc = wn + j*16 + mr;
                float bb = b1[c0 + cloc];
                #pragma unroll
                for (int i = 0; i < 8; ++i)
                    #pragma unroll
                    for (int reg = 0; reg < 4; ++reg)
                        Cs[(i*16 + quad*4 + reg)*136 + cloc] =
                            f2bf(gelu_exact(acc[i][j][reg] + bb));
            }
        }
        __syncthreads();
        #pragma unroll
        for (int it = 0; it < 8; ++it) {
            int idx = t + it*256;
            int r = idx >> 4, f = idx & 15;
            *(float4*)&G[(row0 + half*128 + r)*256 + cl0 + f*8] = *(const float4*)&Cs[r*136 + f*8];
        }
        __syncthreads();
    }
}

// ---------------- K7: dec2 MFMA GEMM + bias -> d_out, 128x128 + prefetch ----------
__global__ __launch_bounds__(256) void k_dec2m(float* ws, void* out, const void* lng)
{
    const int isbf = probe_bf16(lng);
    __shared__ unsigned short SM[18432];
    unsigned short (*As)[72] = (unsigned short(*)[72])SM;
    unsigned short (*Bs)[72] = (unsigned short(*)[72])(SM + 9216);
    unsigned short* Cs = SM;
    const unsigned short* G0  = (const unsigned short*)(ws + OFF_G0);
    const unsigned short* G1  = (const unsigned short*)(ws + OFF_G1);
    const unsigned short* W2B = (const unsigned short*)(ws + OFF_W2B);
    long row0 = (long)blockIdx.x * 128;
    int t = threadIdx.x;
    int lane = t & 63, wv = t >> 6;
    int wm = (wv & 1) * 64, wn = (wv >> 1) * 64;
    int quad = lane >> 4, mr = lane & 15;
    f32x4 acc[4][4] = {};
    float4 pa[4], pb[4];
    #pragma unroll
    for (int it = 0; it < 4; ++it) {
        int idx = t + it*256; int r = idx >> 3, f = idx & 7;
        pa[it] = *(const float4*)&G0[(row0 + r)*256 + f*8];
        pb[it] = *(const float4*)&W2B[(long)r*512 + f*8];
    }
    for (int kc = 0; kc < 8; ++kc) {
        #pragma unroll
        for (int it = 0; it < 4; ++it) {
            int idx = t + it*256; int r = idx >> 3, f = idx & 7;
            *(float4*)&As[r][f*8] = pa[it];
            *(float4*)&Bs[r][f*8] = pb[it];
        }
        __syncthreads();
        if (kc < 7) {
            int k0 = (kc + 1) * 64;
            const unsigned short* Gsrc = (kc + 1 < 4) ? G0 : G1;
            int kl = (kc + 1 < 4) ? k0 : (k0 - 256);
            #pragma unroll
            for (int it = 0; it < 4; ++it) {
                int idx = t + it*256; int r = idx >> 3, f = idx & 7;
                pa[it] = *(const float4*)&Gsrc[(row0 + r)*256 + kl + f*8];
                pb[it] = *(const float4*)&W2B[(long)r*512 + k0 + f*8];
            }
        }
        #pragma unroll
        for (int ks = 0; ks < 64; ks += 32) {
            bf16x8 af[4], bfr[4];
            #pragma unroll
            for (int i = 0; i < 4; ++i)
                af[i] = *(const bf16x8*)&As[wm + i*16 + mr][ks + quad*8];
            #pragma unroll
            for (int j = 0; j < 4; ++j)
                bfr[j] = *(const bf16x8*)&Bs[wn + j*16 + mr][ks + quad*8];
            #pragma unroll
            for (int i = 0; i < 4; ++i)
                #pragma unroll
                for (int j = 0; j < 4; ++j)
                    acc[i][j] = __builtin_amdgcn_mfma_f32_16x16x32_bf16(af[i], bfr[j], acc[i][j], 0, 0, 0);
        }
        __syncthreads();
    }
    const float* b2 = ws + OFF_B2;
    if (isbf) {
        #pragma unroll
        for (int j = 0; j < 4; ++j) {
            int cloc = wn + j*16 + mr;
            float bb = b2[cloc];
            #pragma unroll
            for (int i = 0; i < 4; ++i)
                #pragma unroll
                for (int reg = 0; reg < 4; ++reg)
                    Cs[(wm + i*16 + quad*4 + reg)*136 + cloc] = f2bf(acc[i][j][reg] + bb);
        }
        __syncthreads();
        for (int idx = t; idx < 128*25; idx += 256) {
            int r = idx / 25, f = idx % 25;
            uint2* dst = (uint2*)((char*)out + (row0 + r)*200);
            dst[f] = *(const uint2*)&Cs[r*136 + f*4];
        }
    } else {
        #pragma unroll
        for (int j = 0; j < 4; ++j) {
            int col = wn + j*16 + mr;
            if (col < 100) {
                float bb = b2[col];
                #pragma unroll
                for (int i = 0; i < 4; ++i)
                    #pragma unroll
                    for (int reg = 0; reg < 4; ++reg) {
                        long row = row0 + wm + i*16 + quad*4 + reg;
                        ((float*)out)[row * 100 + col] = acc[i][j][reg] + bb;
                    }
            }
        }
    }
}

extern "C" void kernel_launch(void* const* d_in, const int* in_sizes, int n_in,
                              void* d_out, int out_size, void* d_ws, size_t ws_size,
                              hipStream_t stream)
{
    float* ws = (float*)d_ws;
    k_prep<<<512, 256, 0, stream>>>(d_in[1], d_in[2], d_in[3], d_in[4], d_in[5],
                                    d_in[6], d_in[7], d_in[8], d_in[9], d_in[10],
                                    d_in[11], d_in[12], d_in[13], d_in[14],
                                    d_in[15], d_in[16], ws);
    k_tker<<<256, 256, 0, stream>>>(ws);
    k_encm<<<1024, 256, 0, stream>>>(d_in[0], d_in[11], ws);
    k_state<<<2048, 256, 0, stream>>>(ws);
    k_chunk<<<512, 256, 0, stream>>>(ws);
    k_y<<<2048, 256, 0, stream>>>(ws);
    k_ln2<<<NCH, 1024, 0, stream>>>(ws);
    k_dec1m<<<1024, 256, 0, stream>>>(ws);
    k_dec2m<<<512, 256, 0, stream>>>(ws, d_out, d_in[11]);
}